// Round 7
// baseline (364.476 us; speedup 1.0000x reference)
//
#include <hip/hip_runtime.h>

#define IC 32
#define HW 4096
#define CHW (IC*HW)
#define NG 256
#define EPS 1e-5f
#define GCSZ 4432            // per-group consts: HM(2048) WM(2048) Wc(288 @4096) aw2(32 @4384) bconst(@4416)
#define WS_ROWCOL ((size_t)0)
#define WS_GC   ((size_t)NG*IC*132)
#define WS_CI   (WS_GC + (size_t)NG*GCSZ)
#define WS_KA   (WS_CI + (size_t)NG*IC)

__device__ __forceinline__ float sigmoidf(float x){ return 1.0f/(1.0f+__expf(-x)); }
__device__ __forceinline__ float4 zero4(){ float4 z; z.x=z.y=z.z=z.w=0.f; return z; }

// ---------------- K1: per (group,channel) row/col sums + corners ----------------
__global__ __launch_bounds__(256)
void k1_rowcol(const float* __restrict__ x, float* __restrict__ ws)
{
  const int gid = blockIdx.x;                 // g*32 + i
  const float* __restrict__ p = x + (size_t)gid*HW;
  const int t = threadIdx.x;
  const int tx16 = t & 15, trow = t >> 4;

  __shared__ float rowS[64];
  __shared__ float4 colscr[4][16];
  __shared__ float corn4[4];

  float4 ca; ca.x=ca.y=ca.z=ca.w=0.f;
  #pragma unroll
  for (int k = 0; k < 4; ++k){
    const int r = k*16 + trow;
    float4 v = *(const float4*)(p + r*64 + 4*tx16);
    float rs = v.x+v.y+v.z+v.w;
    rs += __shfl_xor(rs,1); rs += __shfl_xor(rs,2);
    rs += __shfl_xor(rs,4); rs += __shfl_xor(rs,8);
    if (tx16 == 0) rowS[r] = rs;
    ca.x+=v.x; ca.y+=v.y; ca.z+=v.z; ca.w+=v.w;
    if (r == 0){
      if (tx16==0)  corn4[0]=v.x;
      if (tx16==15) corn4[1]=v.w;
    } else if (r == 63){
      if (tx16==0)  corn4[2]=v.x;
      if (tx16==15) corn4[3]=v.w;
    }
  }
  ca.x += __shfl_xor(ca.x,16); ca.y += __shfl_xor(ca.y,16);
  ca.z += __shfl_xor(ca.z,16); ca.w += __shfl_xor(ca.w,16);
  ca.x += __shfl_xor(ca.x,32); ca.y += __shfl_xor(ca.y,32);
  ca.z += __shfl_xor(ca.z,32); ca.w += __shfl_xor(ca.w,32);
  if ((t&63) < 16) colscr[t>>6][tx16] = ca;
  __syncthreads();

  float* base = ws + WS_ROWCOL + (size_t)gid*132;
  if (t < 64) base[t] = rowS[t];
  if (t < 16){
    float4 a = colscr[0][t], b = colscr[1][t], c = colscr[2][t], d = colscr[3][t];
    float4 s;
    s.x=a.x+b.x+c.x+d.x; s.y=a.y+b.y+c.y+d.y;
    s.z=a.z+b.z+c.z+d.z; s.w=a.w+b.w+c.w+d.w;
    *(float4*)(base + 64 + 4*t) = s;
  }
  if (t < 4) base[128+t] = corn4[t];
}

// ---------------- K2: per-group masks, aw2, Wc, bconst ----------------
__global__ __launch_bounds__(256)
void k2_masks(const float* __restrict__ sf_w, const float* __restrict__ sf_b,
              const float* __restrict__ lc_w, const float* __restrict__ lc_b,
              const float* __restrict__ gn_b, float* __restrict__ ws)
{
  __shared__ float P[IC][128];
  __shared__ float corn[IC][4];
  __shared__ float Ts[IC], ga2v[IC], awgs[IC];
  const int t = threadIdx.x;
  const int g = blockIdx.x;
  const float* __restrict__ rc = ws + WS_ROWCOL + (size_t)g*IC*132;
  float* __restrict__ gc = ws + WS_GC + (size_t)g*GCSZ;

  for (int idx=t; idx<IC*132; idx+=256){
    const int ch = idx/132, j = idx - 132*ch;
    const float v = rc[idx];
    if (j < 128) P[ch][j] = v*(1.f/64.f);
    else corn[ch][j-128] = v;
  }
  __syncthreads();

  {
    const int l  = t & 127;
    const int ob = (t >> 7) << 4;
    float acc[16];
    #pragma unroll
    for (int q=0;q<16;q++) acc[q] = sf_b[ob+q];
    for (int i=0;i<IC;i++){
      const float p = P[i][l];
      #pragma unroll
      for (int q=0;q<16;q++) acc[q] = fmaf(sf_w[(ob+q)*IC+i], p, acc[q]);
    }
    #pragma unroll
    for (int q=0;q<16;q++){
      const float s = sigmoidf(acc[q]);
      const int ch = ob+q;
      if (l < 64) gc[ch*64 + l] = s;
      else        gc[2048 + ch*64 + (l-64)] = s;
    }
  }
  if (t < IC){
    float tt = 0.f;
    #pragma unroll
    for (int r4=0;r4<16;r4++){
      float4 v = *(const float4*)&P[t][4*r4];
      tt += v.x+v.y+v.z+v.w;
    }
    Ts[t] = tt * 64.0f;
  }
  __syncthreads();

  {
    const int o = t >> 3, sl = t & 7;
    float dot = 0.f;
    #pragma unroll
    for (int ii=0; ii<4; ii++){
      const int i = sl + 8*ii;
      const float T   = Ts[i];
      const float r0  = 64.f*P[i][0],  r63 = 64.f*P[i][63];
      const float c0  = 64.f*P[i][64], c63 = 64.f*P[i][127];
      const float* w  = lc_w + (o*IC+i)*9;
      const float rex[3] = {r63, 0.f, r0};
      const float cex[3] = {c63, 0.f, c0};
      const float crn[3][3] = {{corn[i][3],0.f,corn[i][2]},
                               {0.f,0.f,0.f},
                               {corn[i][1],0.f,corn[i][0]}};
      #pragma unroll
      for (int ky=0;ky<3;ky++)
        #pragma unroll
        for (int kx=0;kx<3;kx++){
          const float S = T - rex[ky] - cex[kx] + crn[ky][kx];
          dot = fmaf(w[ky*3+kx], S, dot);
        }
    }
    dot += __shfl_xor(dot,1); dot += __shfl_xor(dot,2); dot += __shfl_xor(dot,4);
    if (sl == 0) ga2v[o] = lc_b[o] + dot*(1.0f/4096.0f);
  }
  __syncthreads();

  if (t < IC){
    const int o = t;
    float a = ga2v[o];
    float m = a;
    m = fmaxf(m,__shfl_xor(m,1,32)); m = fmaxf(m,__shfl_xor(m,2,32));
    m = fmaxf(m,__shfl_xor(m,4,32)); m = fmaxf(m,__shfl_xor(m,8,32));
    m = fmaxf(m,__shfl_xor(m,16,32));
    float e = __expf(a-m);
    float s = e;
    s += __shfl_xor(s,1,32); s += __shfl_xor(s,2,32); s += __shfl_xor(s,4,32);
    s += __shfl_xor(s,8,32); s += __shfl_xor(s,16,32);
    gc[4384 + o] = e/s;                       // aw2

    float gb = gn_b[o];
    float m2 = gb;
    m2 = fmaxf(m2,__shfl_xor(m2,1,32)); m2 = fmaxf(m2,__shfl_xor(m2,2,32));
    m2 = fmaxf(m2,__shfl_xor(m2,4,32)); m2 = fmaxf(m2,__shfl_xor(m2,8,32));
    m2 = fmaxf(m2,__shfl_xor(m2,16,32));
    float e2 = __expf(gb-m2);
    float s2 = e2;
    s2 += __shfl_xor(s2,1,32); s2 += __shfl_xor(s2,2,32); s2 += __shfl_xor(s2,4,32);
    s2 += __shfl_xor(s2,8,32); s2 += __shfl_xor(s2,16,32);
    const float aw = e2/s2;
    awgs[o] = aw;
    float bc = aw * lc_b[o];
    bc += __shfl_xor(bc,1,32); bc += __shfl_xor(bc,2,32); bc += __shfl_xor(bc,4,32);
    bc += __shfl_xor(bc,8,32); bc += __shfl_xor(bc,16,32);
    if (o==0) gc[4416] = bc;                  // bconst
  }
  __syncthreads();

  for (int e = t; e < IC*9; e += 256){
    const int i = e/9, k = e - 9*i;
    float acc = 0.f;
    for (int o=0;o<IC;o++) acc = fmaf(awgs[o], lc_w[(o*IC+i)*9+k], acc);
    gc[4096 + e] = acc;                       // Wc
  }
}

// ---------------- K2b: per (group,channel) masked GN stats -> ci, kadd ----------------
__global__ __launch_bounds__(256)
void k2b_stats(const float* __restrict__ x, const float* __restrict__ gn_w,
               const float* __restrict__ gn_b, float* __restrict__ ws)
{
  const int blk = blockIdx.x;                  // g*32 + ch
  const int g = blk >> 5, ch = blk & 31;
  const float* __restrict__ p = x + (size_t)blk*HW;
  const float* __restrict__ gc = ws + WS_GC + (size_t)g*GCSZ;
  __shared__ float hm[64], wm[64];
  __shared__ float red[8];
  const int t = threadIdx.x, tx16 = t & 15, trow = t >> 4;

  if (t < 64) hm[t] = gc[ch*64 + t];
  else if (t < 128) wm[t-64] = gc[2048 + ch*64 + (t-64)];
  __syncthreads();

  const float4 wm4 = *(const float4*)&wm[4*tx16];
  float s1 = 0.f, s2 = 0.f;
  #pragma unroll
  for (int k=0;k<4;k++){
    const int r = k*16 + trow;
    float4 v = *(const float4*)(p + r*64 + 4*tx16);
    const float h = hm[r];
    const float mx = v.x*h*wm4.x, my = v.y*h*wm4.y,
                mz = v.z*h*wm4.z, mw = v.w*h*wm4.w;
    s1 += mx+my+mz+mw;
    s2 += mx*mx+my*my+mz*mz+mw*mw;
  }
  #pragma unroll
  for (int msk=1; msk<64; msk<<=1){
    s1 += __shfl_xor(s1, msk);
    s2 += __shfl_xor(s2, msk);
  }
  if ((t&63)==0){ red[(t>>6)*2] = s1; red[(t>>6)*2+1] = s2; }
  __syncthreads();
  if (t == 0){
    const float S1 = red[0]+red[2]+red[4]+red[6];
    const float S2 = red[1]+red[3]+red[5]+red[7];
    const float mean = S1*(1.f/HW);
    const float var  = fmaxf(S2*(1.f/HW) - mean*mean, 0.f);
    const float rstd = rsqrtf(var + EPS);
    const float a2 = gc[4384+ch], gw = gn_w[ch], gb = gn_b[ch];
    ws[WS_CI + blk] = a2*gw*rstd;
    ws[WS_KA + blk] = a2*(gb - gw*rstd*mean);
  }
}

// ---------------- K3: fused conv + alpha + gate + apply ----------------
// No LDS tile, no barriers in the channel loop: the 3x6 window comes straight from
// global (L1/L2-resident after k1/k2b). Compiler is free to pipeline loads across
// channel iterations; 16 waves/CU hide the L1/L2 latency.
__global__ __launch_bounds__(256)
void k3_fused(const float* __restrict__ x, const float* __restrict__ ws,
              float* __restrict__ out)
{
  const int blk = blockIdx.x;
  const int g = blk >> 2, band = blk & 3;
  const int r0 = band*16;
  const float* __restrict__ xg = x + (size_t)g*CHW;
  float* __restrict__ og = out + (size_t)g*CHW;
  const float* __restrict__ gc = ws + WS_GC + (size_t)g*GCSZ;

  __shared__ float HMs[IC][16];
  __shared__ float WMs[IC][64];
  __shared__ float WcL[IC*9];
  __shared__ float ciL[IC], kaL[IC];

  const int t = threadIdx.x;
  const int ty = t >> 4, tx = t & 15;   // ty: row in band (0..15); tx: float4-chunk (0..15)

  for (int idx=t; idx<512; idx+=256) HMs[idx>>4][idx&15] = gc[(idx>>4)*64 + r0 + (idx&15)];
  for (int idx=t; idx<2048; idx+=256) WMs[idx>>6][idx&63] = gc[2048 + idx];
  for (int e=t; e<IC*9; e+=256) WcL[e] = gc[4096 + e];
  if (t < IC){ ciL[t] = ws[WS_CI + g*IC + t]; kaL[t] = ws[WS_KA + g*IC + t]; }
  __syncthreads();

  float Ksum = gc[4416];
  #pragma unroll
  for (int i=0;i<IC;i++) Ksum += kaL[i];

  const int gr0 = r0 + ty;       // this thread's output row
  const int c0  = 4*tx;
  const bool hasL = (tx > 0), hasR = (tx < 15);

  float logit[4] = {0.f,0.f,0.f,0.f};

  #pragma unroll 2
  for (int i=0;i<IC;i++){
    const float* __restrict__ xi = xg + (size_t)i*HW;
    float row[3][6];
    #pragma unroll
    for (int dr=0; dr<3; dr++){
      const int gr = gr0 + dr - 1;
      if (gr >= 0 && gr < 64){
        const float* rp = xi + gr*64 + c0;
        const float4 c = *(const float4*)rp;
        row[dr][1]=c.x; row[dr][2]=c.y; row[dr][3]=c.z; row[dr][4]=c.w;
        row[dr][0] = hasL ? rp[-1] : 0.f;
        row[dr][5] = hasR ? rp[4]  : 0.f;
      } else {
        #pragma unroll
        for (int jj=0;jj<6;jj++) row[dr][jj] = 0.f;
      }
    }

    float wc[9];
    #pragma unroll
    for (int k=0;k<9;k++) wc[k] = WcL[i*9+k];
    const float hm = HMs[i][ty];
    const float ci = ciL[i];
    const float4 wmc = *(const float4*)&WMs[i][c0];
    const float wmv[4] = {wmc.x, wmc.y, wmc.z, wmc.w};
    #pragma unroll
    for (int p=0;p<4;p++){
      float s = 0.f;
      #pragma unroll
      for (int dr=0;dr<3;dr++){
        #pragma unroll
        for (int dc=0;dc<3;dc++){
          s = fmaf(row[dr][p+dc], wc[dr*3+dc], s);
        }
      }
      logit[p] += s + ci*row[1][p+1]*hm*wmv[p];
    }
  }

  // gate + apply
  float4 gate;
  gate.x = sigmoidf(logit[0] + Ksum);
  gate.y = sigmoidf(logit[1] + Ksum);
  gate.z = sigmoidf(logit[2] + Ksum);
  gate.w = sigmoidf(logit[3] + Ksum);

  const int goff = gr0*64 + c0;
  #pragma unroll 4
  for (int i=0;i<IC;i++){
    float4 v = *(const float4*)(xg + i*HW + goff);
    float4 o;
    o.x = v.x*gate.x; o.y = v.y*gate.y; o.z = v.z*gate.z; o.w = v.w*gate.w;
    *(float4*)(og + i*HW + goff) = o;
  }
}

extern "C" void kernel_launch(void* const* d_in, const int* in_sizes, int n_in,
                              void* d_out, int out_size, void* d_ws, size_t ws_size,
                              hipStream_t stream)
{
  (void)in_sizes; (void)n_in; (void)ws_size; (void)out_size;
  const float* x    = (const float*)d_in[0];
  const float* sfw  = (const float*)d_in[1];
  const float* sfb  = (const float*)d_in[2];
  const float* lcw  = (const float*)d_in[3];
  const float* lcb  = (const float*)d_in[4];
  const float* gnw  = (const float*)d_in[5];
  const float* gnb  = (const float*)d_in[6];
  float* wsf = (float*)d_ws;
  float* out = (float*)d_out;

  k1_rowcol<<<NG*IC, 256, 0, stream>>>(x, wsf);
  k2_masks <<<NG,    256, 0, stream>>>(sfw, sfb, lcw, lcb, gnb, wsf);
  k2b_stats<<<NG*IC, 256, 0, stream>>>(x, gnw, gnb, wsf);
  k3_fused <<<NG*4,  256, 0, stream>>>(x, wsf, out);
}

// Round 8
// 354.166 us; speedup vs baseline: 1.0291x; 1.0291x over previous
//
#include <hip/hip_runtime.h>

#define IC 32
#define HW 4096
#define CHW (IC*HW)
#define NG 256
#define EPS 1e-5f
#define GCSZ 4432            // per-group consts: HM(2048) WM(2048) Wc(288 @4096) aw2(32 @4384) bconst(@4416)
#define WS_ROWCOL ((size_t)0)
#define WS_GC   ((size_t)NG*IC*132)
#define WS_CI   (WS_GC + (size_t)NG*GCSZ)
#define WS_KA   (WS_CI + (size_t)NG*IC)

__device__ __forceinline__ float sigmoidf(float x){ return 1.0f/(1.0f+__expf(-x)); }
__device__ __forceinline__ float4 zero4(){ float4 z; z.x=z.y=z.z=z.w=0.f; return z; }

// ---------------- K1: per (group,channel) row/col sums + corners ----------------
__global__ __launch_bounds__(256)
void k1_rowcol(const float* __restrict__ x, float* __restrict__ ws)
{
  const int gid = blockIdx.x;                 // g*32 + i
  const float* __restrict__ p = x + (size_t)gid*HW;
  const int t = threadIdx.x;
  const int tx16 = t & 15, trow = t >> 4;

  __shared__ float rowS[64];
  __shared__ float4 colscr[4][16];
  __shared__ float corn4[4];

  float4 ca; ca.x=ca.y=ca.z=ca.w=0.f;
  #pragma unroll
  for (int k = 0; k < 4; ++k){
    const int r = k*16 + trow;
    float4 v = *(const float4*)(p + r*64 + 4*tx16);
    float rs = v.x+v.y+v.z+v.w;
    rs += __shfl_xor(rs,1); rs += __shfl_xor(rs,2);
    rs += __shfl_xor(rs,4); rs += __shfl_xor(rs,8);
    if (tx16 == 0) rowS[r] = rs;
    ca.x+=v.x; ca.y+=v.y; ca.z+=v.z; ca.w+=v.w;
    if (r == 0){
      if (tx16==0)  corn4[0]=v.x;
      if (tx16==15) corn4[1]=v.w;
    } else if (r == 63){
      if (tx16==0)  corn4[2]=v.x;
      if (tx16==15) corn4[3]=v.w;
    }
  }
  ca.x += __shfl_xor(ca.x,16); ca.y += __shfl_xor(ca.y,16);
  ca.z += __shfl_xor(ca.z,16); ca.w += __shfl_xor(ca.w,16);
  ca.x += __shfl_xor(ca.x,32); ca.y += __shfl_xor(ca.y,32);
  ca.z += __shfl_xor(ca.z,32); ca.w += __shfl_xor(ca.w,32);
  if ((t&63) < 16) colscr[t>>6][tx16] = ca;
  __syncthreads();

  float* base = ws + WS_ROWCOL + (size_t)gid*132;
  if (t < 64) base[t] = rowS[t];
  if (t < 16){
    float4 a = colscr[0][t], b = colscr[1][t], c = colscr[2][t], d = colscr[3][t];
    float4 s;
    s.x=a.x+b.x+c.x+d.x; s.y=a.y+b.y+c.y+d.y;
    s.z=a.z+b.z+c.z+d.z; s.w=a.w+b.w+c.w+d.w;
    *(float4*)(base + 64 + 4*t) = s;
  }
  if (t < 4) base[128+t] = corn4[t];
}

// ---------------- K2: per-group masks, aw2, Wc, bconst ----------------
__global__ __launch_bounds__(256)
void k2_masks(const float* __restrict__ sf_w, const float* __restrict__ sf_b,
              const float* __restrict__ lc_w, const float* __restrict__ lc_b,
              const float* __restrict__ gn_b, float* __restrict__ ws)
{
  __shared__ float P[IC][128];
  __shared__ float corn[IC][4];
  __shared__ float Ts[IC], ga2v[IC], awgs[IC];
  const int t = threadIdx.x;
  const int g = blockIdx.x;
  const float* __restrict__ rc = ws + WS_ROWCOL + (size_t)g*IC*132;
  float* __restrict__ gc = ws + WS_GC + (size_t)g*GCSZ;

  for (int idx=t; idx<IC*132; idx+=256){
    const int ch = idx/132, j = idx - 132*ch;
    const float v = rc[idx];
    if (j < 128) P[ch][j] = v*(1.f/64.f);
    else corn[ch][j-128] = v;
  }
  __syncthreads();

  {
    const int l  = t & 127;
    const int ob = (t >> 7) << 4;
    float acc[16];
    #pragma unroll
    for (int q=0;q<16;q++) acc[q] = sf_b[ob+q];
    for (int i=0;i<IC;i++){
      const float p = P[i][l];
      #pragma unroll
      for (int q=0;q<16;q++) acc[q] = fmaf(sf_w[(ob+q)*IC+i], p, acc[q]);
    }
    #pragma unroll
    for (int q=0;q<16;q++){
      const float s = sigmoidf(acc[q]);
      const int ch = ob+q;
      if (l < 64) gc[ch*64 + l] = s;
      else        gc[2048 + ch*64 + (l-64)] = s;
    }
  }
  if (t < IC){
    float tt = 0.f;
    #pragma unroll
    for (int r4=0;r4<16;r4++){
      float4 v = *(const float4*)&P[t][4*r4];
      tt += v.x+v.y+v.z+v.w;
    }
    Ts[t] = tt * 64.0f;
  }
  __syncthreads();

  {
    const int o = t >> 3, sl = t & 7;
    float dot = 0.f;
    #pragma unroll
    for (int ii=0; ii<4; ii++){
      const int i = sl + 8*ii;
      const float T   = Ts[i];
      const float r0  = 64.f*P[i][0],  r63 = 64.f*P[i][63];
      const float c0  = 64.f*P[i][64], c63 = 64.f*P[i][127];
      const float* w  = lc_w + (o*IC+i)*9;
      const float rex[3] = {r63, 0.f, r0};
      const float cex[3] = {c63, 0.f, c0};
      const float crn[3][3] = {{corn[i][3],0.f,corn[i][2]},
                               {0.f,0.f,0.f},
                               {corn[i][1],0.f,corn[i][0]}};
      #pragma unroll
      for (int ky=0;ky<3;ky++)
        #pragma unroll
        for (int kx=0;kx<3;kx++){
          const float S = T - rex[ky] - cex[kx] + crn[ky][kx];
          dot = fmaf(w[ky*3+kx], S, dot);
        }
    }
    dot += __shfl_xor(dot,1); dot += __shfl_xor(dot,2); dot += __shfl_xor(dot,4);
    if (sl == 0) ga2v[o] = lc_b[o] + dot*(1.0f/4096.0f);
  }
  __syncthreads();

  if (t < IC){
    const int o = t;
    float a = ga2v[o];
    float m = a;
    m = fmaxf(m,__shfl_xor(m,1,32)); m = fmaxf(m,__shfl_xor(m,2,32));
    m = fmaxf(m,__shfl_xor(m,4,32)); m = fmaxf(m,__shfl_xor(m,8,32));
    m = fmaxf(m,__shfl_xor(m,16,32));
    float e = __expf(a-m);
    float s = e;
    s += __shfl_xor(s,1,32); s += __shfl_xor(s,2,32); s += __shfl_xor(s,4,32);
    s += __shfl_xor(s,8,32); s += __shfl_xor(s,16,32);
    gc[4384 + o] = e/s;                       // aw2

    float gb = gn_b[o];
    float m2 = gb;
    m2 = fmaxf(m2,__shfl_xor(m2,1,32)); m2 = fmaxf(m2,__shfl_xor(m2,2,32));
    m2 = fmaxf(m2,__shfl_xor(m2,4,32)); m2 = fmaxf(m2,__shfl_xor(m2,8,32));
    m2 = fmaxf(m2,__shfl_xor(m2,16,32));
    float e2 = __expf(gb-m2);
    float s2 = e2;
    s2 += __shfl_xor(s2,1,32); s2 += __shfl_xor(s2,2,32); s2 += __shfl_xor(s2,4,32);
    s2 += __shfl_xor(s2,8,32); s2 += __shfl_xor(s2,16,32);
    const float aw = e2/s2;
    awgs[o] = aw;
    float bc = aw * lc_b[o];
    bc += __shfl_xor(bc,1,32); bc += __shfl_xor(bc,2,32); bc += __shfl_xor(bc,4,32);
    bc += __shfl_xor(bc,8,32); bc += __shfl_xor(bc,16,32);
    if (o==0) gc[4416] = bc;                  // bconst
  }
  __syncthreads();

  for (int e = t; e < IC*9; e += 256){
    const int i = e/9, k = e - 9*i;
    float acc = 0.f;
    for (int o=0;o<IC;o++) acc = fmaf(awgs[o], lc_w[(o*IC+i)*9+k], acc);
    gc[4096 + e] = acc;                       // Wc
  }
}

// ---------------- K2b: per (group,channel) masked GN stats -> ci, kadd ----------------
__global__ __launch_bounds__(256)
void k2b_stats(const float* __restrict__ x, const float* __restrict__ gn_w,
               const float* __restrict__ gn_b, float* __restrict__ ws)
{
  const int blk = blockIdx.x;                  // g*32 + ch
  const int g = blk >> 5, ch = blk & 31;
  const float* __restrict__ p = x + (size_t)blk*HW;
  const float* __restrict__ gc = ws + WS_GC + (size_t)g*GCSZ;
  __shared__ float hm[64], wm[64];
  __shared__ float red[8];
  const int t = threadIdx.x, tx16 = t & 15, trow = t >> 4;

  if (t < 64) hm[t] = gc[ch*64 + t];
  else if (t < 128) wm[t-64] = gc[2048 + ch*64 + (t-64)];
  __syncthreads();

  const float4 wm4 = *(const float4*)&wm[4*tx16];
  float s1 = 0.f, s2 = 0.f;
  #pragma unroll
  for (int k=0;k<4;k++){
    const int r = k*16 + trow;
    float4 v = *(const float4*)(p + r*64 + 4*tx16);
    const float h = hm[r];
    const float mx = v.x*h*wm4.x, my = v.y*h*wm4.y,
                mz = v.z*h*wm4.z, mw = v.w*h*wm4.w;
    s1 += mx+my+mz+mw;
    s2 += mx*mx+my*my+mz*mz+mw*mw;
  }
  #pragma unroll
  for (int msk=1; msk<64; msk<<=1){
    s1 += __shfl_xor(s1, msk);
    s2 += __shfl_xor(s2, msk);
  }
  if ((t&63)==0){ red[(t>>6)*2] = s1; red[(t>>6)*2+1] = s2; }
  __syncthreads();
  if (t == 0){
    const float S1 = red[0]+red[2]+red[4]+red[6];
    const float S2 = red[1]+red[3]+red[5]+red[7];
    const float mean = S1*(1.f/HW);
    const float var  = fmaxf(S2*(1.f/HW) - mean*mean, 0.f);
    const float rstd = rsqrtf(var + EPS);
    const float a2 = gc[4384+ch], gw = gn_w[ch], gb = gn_b[ch];
    ws[WS_CI + blk] = a2*gw*rstd;
    ws[WS_KA + blk] = a2*(gb - gw*rstd*mean);
  }
}

// ---------------- K3: fused conv + alpha + gate + apply ----------------
// 2-row x 4-col register patch per thread, 32-row bands (512 blocks, 2/CU).
// Per channel: 4 aligned float4 loads (0.5 VMEM/output), horizontal halo via
// __shfl of already-loaded registers, block-uniform Wc/ci/ka via s_load from
// global. Zero barriers in the loop -> loads pipeline across channels.
__global__ __launch_bounds__(256)
void k3_fused(const float* __restrict__ x, const float* __restrict__ ws,
              float* __restrict__ out)
{
  const int blk = blockIdx.x;
  const int g = blk >> 1, band = blk & 1;
  const int r0 = band*32;
  const float* __restrict__ xg = x + (size_t)g*CHW;
  float* __restrict__ og = out + (size_t)g*CHW;
  const float* __restrict__ gc = ws + WS_GC + (size_t)g*GCSZ;
  const float* __restrict__ gcWc = gc + 4096;          // uniform -> s_load
  const float* __restrict__ ciG  = ws + WS_CI + (size_t)g*IC;
  const float* __restrict__ kaG  = ws + WS_KA + (size_t)g*IC;

  __shared__ float HMs[IC][32];
  __shared__ float WMs[IC][64];

  const int t = threadIdx.x;
  const int ty = t >> 4, tx = t & 15;   // ty: row-pair (0..15); tx: float4-chunk (0..15)

  for (int idx=t; idx<IC*32; idx+=256) HMs[idx>>5][idx&31] = gc[(idx>>5)*64 + r0 + (idx&31)];
  for (int idx=t; idx<IC*64; idx+=256) WMs[idx>>6][idx&63] = gc[2048 + idx];
  __syncthreads();

  float Ksum = gc[4416];
  #pragma unroll
  for (int i=0;i<IC;i++) Ksum += kaG[i];

  const int gr0 = r0 + 2*ty;           // first output row of this thread
  const int c0  = 4*tx;
  const bool hasL = (tx > 0), hasR = (tx < 15);

  float logit[2][4] = {{0.f,0.f,0.f,0.f},{0.f,0.f,0.f,0.f}};

  #pragma unroll 2
  for (int i=0;i<IC;i++){
    const float* __restrict__ xi = xg + (size_t)i*HW;
    float4 v[4];
    float lf[4], rt[4];
    #pragma unroll
    for (int dr=0; dr<4; dr++){
      const int gr = gr0 - 1 + dr;
      if (gr >= 0 && gr < 64) v[dr] = *(const float4*)(xi + gr*64 + c0);
      else v[dr] = zero4();
    }
    #pragma unroll
    for (int dr=0; dr<4; dr++){
      const float l = __shfl_up(v[dr].w, 1);
      const float r = __shfl_down(v[dr].x, 1);
      lf[dr] = hasL ? l : 0.f;
      rt[dr] = hasR ? r : 0.f;
    }

    float wc[9];
    #pragma unroll
    for (int k=0;k<9;k++) wc[k] = gcWc[i*9+k];          // uniform, SGPR
    const float ci = ciG[i];                            // uniform, SGPR
    const float4 wmc = *(const float4*)&WMs[i][c0];
    const float wmv[4] = {wmc.x, wmc.y, wmc.z, wmc.w};

    // w6(r, j): 6-wide window row r, col j in [lf | x y z w | rt]
    #define W6(r_, j_) ((j_)==0 ? lf[r_] : (j_)==1 ? v[r_].x : (j_)==2 ? v[r_].y : \
                        (j_)==3 ? v[r_].z : (j_)==4 ? v[r_].w : rt[r_])
    #pragma unroll
    for (int q=0;q<2;q++){
      const float hm = HMs[i][2*ty+q];
      #pragma unroll
      for (int p=0;p<4;p++){
        float s = 0.f;
        #pragma unroll
        for (int dr=0;dr<3;dr++){
          #pragma unroll
          for (int dc=0;dc<3;dc++){
            s = fmaf(W6(q+dr, p+dc), wc[dr*3+dc], s);
          }
        }
        logit[q][p] += s + ci*W6(q+1, p+1)*hm*wmv[p];
      }
    }
    #undef W6
  }

  // gate + apply
  float gate[2][4];
  #pragma unroll
  for (int q=0;q<2;q++)
    #pragma unroll
    for (int p=0;p<4;p++)
      gate[q][p] = sigmoidf(logit[q][p] + Ksum);

  const int goff = gr0*64 + c0;
  #pragma unroll 4
  for (int i=0;i<IC;i++){
    #pragma unroll
    for (int q=0;q<2;q++){
      float4 vv = *(const float4*)(xg + i*HW + goff + q*64);
      float4 o;
      o.x = vv.x*gate[q][0]; o.y = vv.y*gate[q][1];
      o.z = vv.z*gate[q][2]; o.w = vv.w*gate[q][3];
      *(float4*)(og + i*HW + goff + q*64) = o;
    }
  }
}

extern "C" void kernel_launch(void* const* d_in, const int* in_sizes, int n_in,
                              void* d_out, int out_size, void* d_ws, size_t ws_size,
                              hipStream_t stream)
{
  (void)in_sizes; (void)n_in; (void)ws_size; (void)out_size;
  const float* x    = (const float*)d_in[0];
  const float* sfw  = (const float*)d_in[1];
  const float* sfb  = (const float*)d_in[2];
  const float* lcw  = (const float*)d_in[3];
  const float* lcb  = (const float*)d_in[4];
  const float* gnw  = (const float*)d_in[5];
  const float* gnb  = (const float*)d_in[6];
  float* wsf = (float*)d_ws;
  float* out = (float*)d_out;

  k1_rowcol<<<NG*IC, 256, 0, stream>>>(x, wsf);
  k2_masks <<<NG,    256, 0, stream>>>(sfw, sfb, lcw, lcb, gnb, wsf);
  k2b_stats<<<NG*IC, 256, 0, stream>>>(x, gnw, gnb, wsf);
  k3_fused <<<NG*2,  256, 0, stream>>>(x, wsf, out);
}

// Round 9
// 330.582 us; speedup vs baseline: 1.1025x; 1.0713x over previous
//
#include <hip/hip_runtime.h>

#define IC 32
#define HW 4096
#define CHW (IC*HW)
#define NG 256
#define EPS 1e-5f
#define GCSZ 4432            // per-group consts: HM(2048) WM(2048) Wc(288 @4096) aw2(32 @4384) bconst(@4416)
#define WS_ROWCOL ((size_t)0)
#define WS_GC   ((size_t)NG*IC*132)
#define WS_CI   (WS_GC + (size_t)NG*GCSZ)
#define WS_KA   (WS_CI + (size_t)NG*IC)

__device__ __forceinline__ float sigmoidf(float x){ return 1.0f/(1.0f+__expf(-x)); }
__device__ __forceinline__ float4 zero4(){ float4 z; z.x=z.y=z.z=z.w=0.f; return z; }

// ---------------- K1: per (group,channel) row/col sums + corners ----------------
__global__ __launch_bounds__(256)
void k1_rowcol(const float* __restrict__ x, float* __restrict__ ws)
{
  const int gid = blockIdx.x;                 // g*32 + i
  const float* __restrict__ p = x + (size_t)gid*HW;
  const int t = threadIdx.x;
  const int tx16 = t & 15, trow = t >> 4;

  __shared__ float rowS[64];
  __shared__ float4 colscr[4][16];
  __shared__ float corn4[4];

  float4 ca; ca.x=ca.y=ca.z=ca.w=0.f;
  #pragma unroll
  for (int k = 0; k < 4; ++k){
    const int r = k*16 + trow;
    float4 v = *(const float4*)(p + r*64 + 4*tx16);
    float rs = v.x+v.y+v.z+v.w;
    rs += __shfl_xor(rs,1); rs += __shfl_xor(rs,2);
    rs += __shfl_xor(rs,4); rs += __shfl_xor(rs,8);
    if (tx16 == 0) rowS[r] = rs;
    ca.x+=v.x; ca.y+=v.y; ca.z+=v.z; ca.w+=v.w;
    if (r == 0){
      if (tx16==0)  corn4[0]=v.x;
      if (tx16==15) corn4[1]=v.w;
    } else if (r == 63){
      if (tx16==0)  corn4[2]=v.x;
      if (tx16==15) corn4[3]=v.w;
    }
  }
  ca.x += __shfl_xor(ca.x,16); ca.y += __shfl_xor(ca.y,16);
  ca.z += __shfl_xor(ca.z,16); ca.w += __shfl_xor(ca.w,16);
  ca.x += __shfl_xor(ca.x,32); ca.y += __shfl_xor(ca.y,32);
  ca.z += __shfl_xor(ca.z,32); ca.w += __shfl_xor(ca.w,32);
  if ((t&63) < 16) colscr[t>>6][tx16] = ca;
  __syncthreads();

  float* base = ws + WS_ROWCOL + (size_t)gid*132;
  if (t < 64) base[t] = rowS[t];
  if (t < 16){
    float4 a = colscr[0][t], b = colscr[1][t], c = colscr[2][t], d = colscr[3][t];
    float4 s;
    s.x=a.x+b.x+c.x+d.x; s.y=a.y+b.y+c.y+d.y;
    s.z=a.z+b.z+c.z+d.z; s.w=a.w+b.w+c.w+d.w;
    *(float4*)(base + 64 + 4*t) = s;
  }
  if (t < 4) base[128+t] = corn4[t];
}

// ---------------- K2: per-group masks, aw2, Wc, bconst ----------------
__global__ __launch_bounds__(256)
void k2_masks(const float* __restrict__ sf_w, const float* __restrict__ sf_b,
              const float* __restrict__ lc_w, const float* __restrict__ lc_b,
              const float* __restrict__ gn_b, float* __restrict__ ws)
{
  __shared__ float P[IC][128];
  __shared__ float corn[IC][4];
  __shared__ float Ts[IC], ga2v[IC], awgs[IC];
  const int t = threadIdx.x;
  const int g = blockIdx.x;
  const float* __restrict__ rc = ws + WS_ROWCOL + (size_t)g*IC*132;
  float* __restrict__ gc = ws + WS_GC + (size_t)g*GCSZ;

  for (int idx=t; idx<IC*132; idx+=256){
    const int ch = idx/132, j = idx - 132*ch;
    const float v = rc[idx];
    if (j < 128) P[ch][j] = v*(1.f/64.f);
    else corn[ch][j-128] = v;
  }
  __syncthreads();

  {
    const int l  = t & 127;
    const int ob = (t >> 7) << 4;
    float acc[16];
    #pragma unroll
    for (int q=0;q<16;q++) acc[q] = sf_b[ob+q];
    for (int i=0;i<IC;i++){
      const float p = P[i][l];
      #pragma unroll
      for (int q=0;q<16;q++) acc[q] = fmaf(sf_w[(ob+q)*IC+i], p, acc[q]);
    }
    #pragma unroll
    for (int q=0;q<16;q++){
      const float s = sigmoidf(acc[q]);
      const int ch = ob+q;
      if (l < 64) gc[ch*64 + l] = s;
      else        gc[2048 + ch*64 + (l-64)] = s;
    }
  }
  if (t < IC){
    float tt = 0.f;
    #pragma unroll
    for (int r4=0;r4<16;r4++){
      float4 v = *(const float4*)&P[t][4*r4];
      tt += v.x+v.y+v.z+v.w;
    }
    Ts[t] = tt * 64.0f;
  }
  __syncthreads();

  {
    const int o = t >> 3, sl = t & 7;
    float dot = 0.f;
    #pragma unroll
    for (int ii=0; ii<4; ii++){
      const int i = sl + 8*ii;
      const float T   = Ts[i];
      const float r0  = 64.f*P[i][0],  r63 = 64.f*P[i][63];
      const float c0  = 64.f*P[i][64], c63 = 64.f*P[i][127];
      const float* w  = lc_w + (o*IC+i)*9;
      const float rex[3] = {r63, 0.f, r0};
      const float cex[3] = {c63, 0.f, c0};
      const float crn[3][3] = {{corn[i][3],0.f,corn[i][2]},
                               {0.f,0.f,0.f},
                               {corn[i][1],0.f,corn[i][0]}};
      #pragma unroll
      for (int ky=0;ky<3;ky++)
        #pragma unroll
        for (int kx=0;kx<3;kx++){
          const float S = T - rex[ky] - cex[kx] + crn[ky][kx];
          dot = fmaf(w[ky*3+kx], S, dot);
        }
    }
    dot += __shfl_xor(dot,1); dot += __shfl_xor(dot,2); dot += __shfl_xor(dot,4);
    if (sl == 0) ga2v[o] = lc_b[o] + dot*(1.0f/4096.0f);
  }
  __syncthreads();

  if (t < IC){
    const int o = t;
    float a = ga2v[o];
    float m = a;
    m = fmaxf(m,__shfl_xor(m,1,32)); m = fmaxf(m,__shfl_xor(m,2,32));
    m = fmaxf(m,__shfl_xor(m,4,32)); m = fmaxf(m,__shfl_xor(m,8,32));
    m = fmaxf(m,__shfl_xor(m,16,32));
    float e = __expf(a-m);
    float s = e;
    s += __shfl_xor(s,1,32); s += __shfl_xor(s,2,32); s += __shfl_xor(s,4,32);
    s += __shfl_xor(s,8,32); s += __shfl_xor(s,16,32);
    gc[4384 + o] = e/s;                       // aw2

    float gb = gn_b[o];
    float m2 = gb;
    m2 = fmaxf(m2,__shfl_xor(m2,1,32)); m2 = fmaxf(m2,__shfl_xor(m2,2,32));
    m2 = fmaxf(m2,__shfl_xor(m2,4,32)); m2 = fmaxf(m2,__shfl_xor(m2,8,32));
    m2 = fmaxf(m2,__shfl_xor(m2,16,32));
    float e2 = __expf(gb-m2);
    float s2 = e2;
    s2 += __shfl_xor(s2,1,32); s2 += __shfl_xor(s2,2,32); s2 += __shfl_xor(s2,4,32);
    s2 += __shfl_xor(s2,8,32); s2 += __shfl_xor(s2,16,32);
    const float aw = e2/s2;
    awgs[o] = aw;
    float bc = aw * lc_b[o];
    bc += __shfl_xor(bc,1,32); bc += __shfl_xor(bc,2,32); bc += __shfl_xor(bc,4,32);
    bc += __shfl_xor(bc,8,32); bc += __shfl_xor(bc,16,32);
    if (o==0) gc[4416] = bc;                  // bconst
  }
  __syncthreads();

  for (int e = t; e < IC*9; e += 256){
    const int i = e/9, k = e - 9*i;
    float acc = 0.f;
    for (int o=0;o<IC;o++) acc = fmaf(awgs[o], lc_w[(o*IC+i)*9+k], acc);
    gc[4096 + e] = acc;                       // Wc
  }
}

// ---------------- K2b: per (group,channel) masked GN stats -> ci, kadd ----------------
__global__ __launch_bounds__(256)
void k2b_stats(const float* __restrict__ x, const float* __restrict__ gn_w,
               const float* __restrict__ gn_b, float* __restrict__ ws)
{
  const int blk = blockIdx.x;                  // g*32 + ch
  const int g = blk >> 5, ch = blk & 31;
  const float* __restrict__ p = x + (size_t)blk*HW;
  const float* __restrict__ gc = ws + WS_GC + (size_t)g*GCSZ;
  __shared__ float hm[64], wm[64];
  __shared__ float red[8];
  const int t = threadIdx.x, tx16 = t & 15, trow = t >> 4;

  if (t < 64) hm[t] = gc[ch*64 + t];
  else if (t < 128) wm[t-64] = gc[2048 + ch*64 + (t-64)];
  __syncthreads();

  const float4 wm4 = *(const float4*)&wm[4*tx16];
  float s1 = 0.f, s2 = 0.f;
  #pragma unroll
  for (int k=0;k<4;k++){
    const int r = k*16 + trow;
    float4 v = *(const float4*)(p + r*64 + 4*tx16);
    const float h = hm[r];
    const float mx = v.x*h*wm4.x, my = v.y*h*wm4.y,
                mz = v.z*h*wm4.z, mw = v.w*h*wm4.w;
    s1 += mx+my+mz+mw;
    s2 += mx*mx+my*my+mz*mz+mw*mw;
  }
  #pragma unroll
  for (int msk=1; msk<64; msk<<=1){
    s1 += __shfl_xor(s1, msk);
    s2 += __shfl_xor(s2, msk);
  }
  if ((t&63)==0){ red[(t>>6)*2] = s1; red[(t>>6)*2+1] = s2; }
  __syncthreads();
  if (t == 0){
    const float S1 = red[0]+red[2]+red[4]+red[6];
    const float S2 = red[1]+red[3]+red[5]+red[7];
    const float mean = S1*(1.f/HW);
    const float var  = fmaxf(S2*(1.f/HW) - mean*mean, 0.f);
    const float rstd = rsqrtf(var + EPS);
    const float a2 = gc[4384+ch], gw = gn_w[ch], gb = gn_b[ch];
    ws[WS_CI + blk] = a2*gw*rstd;
    ws[WS_KA + blk] = a2*(gb - gw*rstd*mean);
  }
}

// ---------------- K3: fused conv + alpha + gate + apply ----------------
// 1024 blocks (16-row band, 4/CU) x 256 threads, 1 output row x 4 cols per thread.
// Per channel: 3 aligned float4 loads + 6 shfl for horizontal halo (no scalar
// edge loads, no LDS tile, no barriers). 1-deep software pipeline: channel i+1's
// rows are issued before channel i's compute.
__global__ __launch_bounds__(256)
void k3_fused(const float* __restrict__ x, const float* __restrict__ ws,
              float* __restrict__ out)
{
  const int blk = blockIdx.x;
  const int g = blk >> 2, band = blk & 3;
  const int r0 = band*16;
  const float* __restrict__ xg = x + (size_t)g*CHW;
  float* __restrict__ og = out + (size_t)g*CHW;
  const float* __restrict__ gc = ws + WS_GC + (size_t)g*GCSZ;
  const float* __restrict__ gcWc = gc + 4096;          // uniform -> s_load
  const float* __restrict__ ciG  = ws + WS_CI + (size_t)g*IC;
  const float* __restrict__ kaG  = ws + WS_KA + (size_t)g*IC;

  __shared__ float HMs[IC][16];
  __shared__ float WMs[IC][64];

  const int t = threadIdx.x;
  const int ty = t >> 4, tx = t & 15;   // ty: row in band (0..15); tx: float4-chunk (0..15)

  for (int idx=t; idx<IC*16; idx+=256) HMs[idx>>4][idx&15] = gc[(idx>>4)*64 + r0 + (idx&15)];
  for (int idx=t; idx<IC*64; idx+=256) WMs[idx>>6][idx&63] = gc[2048 + idx];
  __syncthreads();

  float Ksum = gc[4416];
  #pragma unroll
  for (int i=0;i<IC;i++) Ksum += kaG[i];

  const int gr0 = r0 + ty;             // this thread's output row
  const int c0  = 4*tx;
  const bool hasL = (tx > 0), hasR = (tx < 15);
  const bool hasU = (gr0 > 0), hasD = (gr0 < 63);

  float logit[4] = {0.f,0.f,0.f,0.f};

  // software pipeline: load rows for channel 0
  float4 a0, a1, a2;
  {
    const float* xi = xg;
    a1 = *(const float4*)(xi + gr0*64 + c0);
    a0 = hasU ? *(const float4*)(xi + (gr0-1)*64 + c0) : zero4();
    a2 = hasD ? *(const float4*)(xi + (gr0+1)*64 + c0) : zero4();
  }

  for (int i=0;i<IC;i++){
    float4 b0, b1, b2;
    if (i+1 < IC){
      const float* xi = xg + (size_t)(i+1)*HW;
      b1 = *(const float4*)(xi + gr0*64 + c0);
      b0 = hasU ? *(const float4*)(xi + (gr0-1)*64 + c0) : zero4();
      b2 = hasD ? *(const float4*)(xi + (gr0+1)*64 + c0) : zero4();
    } else { b0 = b1 = b2 = zero4(); }

    // horizontal halo via shfl (lane+-1 within 16-lane row-groups; edges masked)
    float lf0 = __shfl_up(a0.w,1), lf1 = __shfl_up(a1.w,1), lf2 = __shfl_up(a2.w,1);
    float rt0 = __shfl_down(a0.x,1), rt1 = __shfl_down(a1.x,1), rt2 = __shfl_down(a2.x,1);
    if (!hasL){ lf0=0.f; lf1=0.f; lf2=0.f; }
    if (!hasR){ rt0=0.f; rt1=0.f; rt2=0.f; }

    float wc[9];
    #pragma unroll
    for (int k=0;k<9;k++) wc[k] = gcWc[i*9+k];          // uniform, SGPR
    const float ci = ciG[i];                            // uniform, SGPR
    const float hm = HMs[i][ty];
    const float4 wmc = *(const float4*)&WMs[i][c0];
    const float wmv[4] = {wmc.x, wmc.y, wmc.z, wmc.w};

    // 6-wide windows per row: [lf | x y z w | rt]
    const float w0[6] = {lf0, a0.x, a0.y, a0.z, a0.w, rt0};
    const float w1[6] = {lf1, a1.x, a1.y, a1.z, a1.w, rt1};
    const float w2[6] = {lf2, a2.x, a2.y, a2.z, a2.w, rt2};

    #pragma unroll
    for (int p=0;p<4;p++){
      float s = 0.f;
      #pragma unroll
      for (int dc=0;dc<3;dc++){
        s = fmaf(w0[p+dc], wc[0*3+dc], s);
        s = fmaf(w1[p+dc], wc[1*3+dc], s);
        s = fmaf(w2[p+dc], wc[2*3+dc], s);
      }
      logit[p] += s + ci*w1[p+1]*hm*wmv[p];
    }

    a0 = b0; a1 = b1; a2 = b2;
  }

  // gate + apply
  float4 gate;
  gate.x = sigmoidf(logit[0] + Ksum);
  gate.y = sigmoidf(logit[1] + Ksum);
  gate.z = sigmoidf(logit[2] + Ksum);
  gate.w = sigmoidf(logit[3] + Ksum);

  const int goff = gr0*64 + c0;
  #pragma unroll 4
  for (int i=0;i<IC;i++){
    float4 v = *(const float4*)(xg + i*HW + goff);
    float4 o;
    o.x = v.x*gate.x; o.y = v.y*gate.y; o.z = v.z*gate.z; o.w = v.w*gate.w;
    *(float4*)(og + i*HW + goff) = o;
  }
}

extern "C" void kernel_launch(void* const* d_in, const int* in_sizes, int n_in,
                              void* d_out, int out_size, void* d_ws, size_t ws_size,
                              hipStream_t stream)
{
  (void)in_sizes; (void)n_in; (void)ws_size; (void)out_size;
  const float* x    = (const float*)d_in[0];
  const float* sfw  = (const float*)d_in[1];
  const float* sfb  = (const float*)d_in[2];
  const float* lcw  = (const float*)d_in[3];
  const float* lcb  = (const float*)d_in[4];
  const float* gnw  = (const float*)d_in[5];
  const float* gnb  = (const float*)d_in[6];
  float* wsf = (float*)d_ws;
  float* out = (float*)d_out;

  k1_rowcol<<<NG*IC, 256, 0, stream>>>(x, wsf);
  k2_masks <<<NG,    256, 0, stream>>>(sfw, sfb, lcw, lcb, gnb, wsf);
  k2b_stats<<<NG*IC, 256, 0, stream>>>(x, gnw, gnb, wsf);
  k3_fused <<<NG*4,  256, 0, stream>>>(x, wsf, out);
}